// Round 5
// baseline (8602.889 us; speedup 1.0000x reference)
//
#include <hip/hip_runtime.h>

// Problem constants (DiffeqSolver: S=1, b=64, N=50, F=64, H=128, K=2, T=40)
#define B_   64
#define N_   50
#define F_   64
#define H_   128
#define T_   40
#define E_   2450      // N*(N-1)
#define EPN  49        // edges per receiving node
#define NSTAGE ((T_ - 1) * 4)   // 156 RK4 stage evals

typedef __attribute__((ext_vector_type(8))) short  short8;   // 8 x bf16
typedef __attribute__((ext_vector_type(4))) float  float4_;  // MFMA accumulator

__device__ __forceinline__ unsigned short f2bf(float x) {
    union { float f; unsigned u; } v; v.f = x;
    unsigned r = v.u + 0x7fffu + ((v.u >> 16) & 1u);   // RNE
    return (unsigned short)(r >> 16);
}
__device__ __forceinline__ float bf2f(unsigned short x) {
    union { unsigned u; float f; } v; v.u = ((unsigned)x) << 16;
    return v.f;
}

// ---------------------------------------------------------------------------
// Setup: transposed bf16 weights: WT[k][j][i] = W[k][i][j]
// ---------------------------------------------------------------------------
__global__ void k_weights(const float* __restrict__ W1, const float* __restrict__ W2,
                          unsigned short* __restrict__ w1t, unsigned short* __restrict__ w2t) {
    int tid = blockIdx.x * 256 + threadIdx.x;
    int mat = tid >> 15;
    int rr  = tid & 32767;
    int k = rr >> 14, i = (rr >> 7) & 127, j = rr & 127;
    const float* src = mat ? W2 : W1;
    unsigned short* dst = mat ? w2t : w1t;
    dst[(((k << 7) | j) << 7) | i] = f2bf(src[(((k << 7) | i) << 7) | j]);
}

__global__ void k_w3(const float* __restrict__ W3, unsigned short* __restrict__ w3t) {
    int tid = blockIdx.x * 256 + threadIdx.x;   // 0 .. 8191
    int f = tid >> 7, h = tid & 127;
    w3t[(f << 7) | h] = f2bf(W3[(h << 6) | f]);
}

// ---------------------------------------------------------------------------
// Setup: counting-sort senders by edge type per (b,n).
// slots[0..g0-1]=type-0, slots[a0..a0+g1-1]=type-1 (a0=ceil16(g0)), rest -1.
// a0w packs a0 | g0<<8 | g1<<16.
// ---------------------------------------------------------------------------
__global__ void k_sort(const int* __restrict__ graph, int* __restrict__ slots,
                       int* __restrict__ a0w) {
    int tid = blockIdx.x * 256 + threadIdx.x;
    if (tid >= B_ * N_) return;
    int b = tid / N_, n = tid % N_;
    const int* g = graph + b * E_ + n * EPN;
    int base = tid * 64;
    for (int j = 0; j < 64; j++) slots[base + j] = -1;
    int g0 = 0;
    for (int j = 0; j < EPN; j++) g0 += (g[j] == 0);
    int a0 = (g0 + 15) & ~15;
    int g1 = EPN - g0;
    a0w[tid] = a0 | (g0 << 8) | (g1 << 16);
    int p0 = 0, p1 = a0;
    for (int j = 0; j < EPN; j++) {
        int s = (j < n) ? j : j + 1;
        if (g[j] == 0) slots[base + (p0++)] = s;
        else           slots[base + (p1++)] = s;
    }
}

// ---------------------------------------------------------------------------
// Persistent kernel, PLAIN launch. 256 blocks; batch b is owned by blocks
// {b, b+64, b+128, b+192} (7/6/6/6 node-pairs). Co-residency is guaranteed:
// 54KB LDS + launch_bounds(256,2) -> capacity >= 2 blocks/CU = 512 >= 256.
// Per-batch sense-free barrier: monotone counter, release add + acquire spin.
// ---------------------------------------------------------------------------
__launch_bounds__(256, 2)
__global__ void k_persist(const float* __restrict__ fp, const float* __restrict__ ts,
                          const int* __restrict__ slotsW, const int* __restrict__ a0W,
                          const unsigned short* __restrict__ w1t,
                          const unsigned short* __restrict__ w2t,
                          const float* __restrict__ b1g, const float* __restrict__ b2g,
                          const unsigned short* __restrict__ w3t,
                          const float* __restrict__ b3,
                          unsigned short* ybG,           // 2 x 204800 ping-pong
                          float* __restrict__ out,
                          int* cnt) {                    // 64 counters, stride 16
    __shared__ unsigned short yb[51][72];     // whole batch y; row 50 = zeros
    __shared__ unsigned short hbuf[128][136]; // layer-1 output (one pair)
    __shared__ int   sltL[7 * 128];           // this block's slots as yb BYTE offsets
    __shared__ int   a0L[14];                 // packed a0|g0|g1 per node
    __shared__ float aggv[2][128];
    __shared__ float Ysh[7 * 128];            // RK4 state y
    __shared__ float Ash[7 * 128];            // RK4 accumulator
    __shared__ float tsL[T_];

    const int tid  = threadIdx.x;
    const int lane = tid & 63;
    const int w    = tid >> 6;
    const int b    = blockIdx.x & 63;
    const int j    = blockIdx.x >> 6;          // peer index 0..3 (stride-64 => same XCD)
    const int pstart = (j == 0) ? 0 : (6 * j + 1);   // {0,7,13,19}
    const int pcnt   = (j == 0) ? 7 : 6;
    const int nodes0 = 2 * pstart;
    const int ncnt   = 2 * pcnt;

    int* cp = cnt + b * 16;

    const int lr = lane & 15;
    const int q  = lane >> 4;
    const int colA = ((2 * w)     << 4) + lr;
    const int colB = ((2 * w + 1) << 4) + lr;

    // biases in registers for the whole run
    float b1A0 = b1g[colA], b1A1 = b1g[128 + colA];
    float b1B0 = b1g[colB], b1B1 = b1g[128 + colB];
    float b2A0 = b2g[colA], b2A1 = b2g[128 + colA];
    float b2B0 = b2g[colB], b2B1 = b2g[128 + colB];
    float b3v  = b3[tid & 63];

    // ---- one-time staging: slots (as byte offsets into yb), a0, ts, state ----
    for (int t2 = tid; t2 < ncnt * 64; t2 += 256) {
        int nl = t2 >> 6, jn = t2 & 63;
        int sv = slotsW[(b * N_ + nodes0 + nl) * 64 + jn];
        sltL[t2] = (sv < 0 ? 50 : sv) * 144;          // row stride = 72 shorts = 144 B
    }
    if (tid < ncnt) a0L[tid] = a0W[b * N_ + nodes0 + tid];
    if (tid < T_)   tsL[tid] = ts[tid];
    if (tid < 72)   yb[50][tid] = 0;                  // zero pad row (written once)
    for (int t2 = tid; t2 < ncnt * 64; t2 += 256) {
        int nl = t2 >> 6, f = t2 & 63;
        int bn = b * N_ + nodes0 + nl;
        float v = fp[bn * F_ + f];
        Ysh[t2] = v;
        ybG[bn * F_ + f] = f2bf(v);
        out[bn * (T_ * F_) + f] = v;
    }
    __syncthreads();
    int gen = 1;
    if (tid == 0) {
        __threadfence();   // make this block's global stores visible device-wide
        __hip_atomic_fetch_add(cp, 1, __ATOMIC_RELEASE, __HIP_MEMORY_SCOPE_AGENT);
        while (__hip_atomic_load(cp, __ATOMIC_ACQUIRE, __HIP_MEMORY_SCOPE_AGENT) < 4 * gen)
            __builtin_amdgcn_s_sleep(2);
        __threadfence();   // acquire: invalidate stale cached lines before re-reading
    }
    __syncthreads();

    const float4_ fz = {0.f, 0.f, 0.f, 0.f};
    const float inv_n = 1.0f / (float)N_;

    #pragma unroll 1
    for (int g = 0; g < NSTAGE; g++) {
        const int t = g >> 2, r = g & 3;
        const float dt = tsL[t + 1] - tsL[t];
        const unsigned short* ybIn = ybG + (g & 1) * (B_ * N_ * F_);
        unsigned short*       ybO  = ybG + ((g & 1) ^ 1) * (B_ * N_ * F_);

        // ---- stage the whole batch y once per stage ----
        const unsigned short* ybb = ybIn + b * (N_ * F_);
        for (int idx2 = tid; idx2 < 400; idx2 += 256) {
            int row = idx2 >> 3, c8 = idx2 & 7;
            *(uint4*)(&yb[row][c8 * 8]) = *(const uint4*)(ybb + row * 64 + c8 * 8);
        }
        __syncthreads();

        #pragma unroll 1
        for (int vp = 0; vp < pcnt; vp++) {
            const int n0 = 2 * (pstart + vp);

            int pk0 = a0L[2 * vp], pk1 = a0L[2 * vp + 1];
            int a0s0 = pk0 & 0xff, a0s1 = pk1 & 0xff;
            int l00 = (pk0 >> 8) & 0xff, l01 = a0s0 + ((pk0 >> 16) & 0xff);
            int l10 = (pk1 >> 8) & 0xff, l11 = a0s1 + ((pk1 >> 16) & 0xff);

            int ktile[8], lim[8], rowO[8];
            #pragma unroll
            for (int tt = 0; tt < 8; tt++) {
                int node = tt >> 2;
                int a0n = node ? a0s1 : a0s0;
                int kt = (((tt & 3) << 4) >= a0n) ? 1 : 0;
                ktile[tt] = kt;
                lim[tt] = node ? (kt ? l11 : l10) : (kt ? l01 : l00);
                rowO[tt] = sltL[((vp << 1) + node) * 64 + ((tt & 3) << 4) + lr];
            }

            // ================= GEMM1 =================
            float4_ acc[8][2];
            #pragma unroll
            for (int tt = 0; tt < 8; tt++) { acc[tt][0] = fz; acc[tt][1] = fz; }

            const char* ybBase = (const char*)(&yb[0][0]);
            #pragma unroll
            for (int kc = 0; kc < 2; kc++) {            // sender K-half
                int kb = (kc << 5) + (q << 3);
                short8 B00 = *(const short8*)(w1t + ((      colA) << 7) + kb);
                short8 B01 = *(const short8*)(w1t + ((128 + colA) << 7) + kb);
                short8 B10 = *(const short8*)(w1t + ((      colB) << 7) + kb);
                short8 B11 = *(const short8*)(w1t + ((128 + colB) << 7) + kb);
                #pragma unroll
                for (int tt = 0; tt < 8; tt++) {
                    short8 a = *(const short8*)(ybBase + rowO[tt] + (kb << 1));
                    short8 Bx0 = ktile[tt] ? B01 : B00;
                    short8 Bx1 = ktile[tt] ? B11 : B10;
                    acc[tt][0] = __builtin_amdgcn_mfma_f32_16x16x32_bf16(a, Bx0, acc[tt][0], 0, 0, 0);
                    acc[tt][1] = __builtin_amdgcn_mfma_f32_16x16x32_bf16(a, Bx1, acc[tt][1], 0, 0, 0);
                }
            }
            #pragma unroll
            for (int kc = 0; kc < 2; kc++) {            // receiver K-half
                int kb  = (kc << 5) + (q << 3);
                int kbW = 64 + kb;
                short8 B00 = *(const short8*)(w1t + ((      colA) << 7) + kbW);
                short8 B01 = *(const short8*)(w1t + ((128 + colA) << 7) + kbW);
                short8 B10 = *(const short8*)(w1t + ((      colB) << 7) + kbW);
                short8 B11 = *(const short8*)(w1t + ((128 + colB) << 7) + kbW);
                short8 aR0 = *(const short8*)(&yb[n0    ][kb]);
                short8 aR1 = *(const short8*)(&yb[n0 + 1][kb]);
                #pragma unroll
                for (int tt = 0; tt < 8; tt++) {
                    short8 a = (tt < 4) ? aR0 : aR1;
                    short8 Bx0 = ktile[tt] ? B01 : B00;
                    short8 Bx1 = ktile[tt] ? B11 : B10;
                    acc[tt][0] = __builtin_amdgcn_mfma_f32_16x16x32_bf16(a, Bx0, acc[tt][0], 0, 0, 0);
                    acc[tt][1] = __builtin_amdgcn_mfma_f32_16x16x32_bf16(a, Bx1, acc[tt][1], 0, 0, 0);
                }
            }
            // epilogue 1: bias + relu -> hbuf
            #pragma unroll
            for (int tt = 0; tt < 8; tt++) {
                int r0 = q << 2;
                #pragma unroll
                for (int cw = 0; cw < 2; cw++) {
                    int col = ((2 * w + cw) << 4) + lr;
                    float bias = ktile[tt] ? (cw ? b1B1 : b1A1) : (cw ? b1B0 : b1A0);
                    #pragma unroll
                    for (int i = 0; i < 4; i++) {
                        float hv = fmaxf(acc[tt][cw][i] + bias, 0.0f);
                        hbuf[(tt << 4) + r0 + i][col] = f2bf(hv);
                    }
                }
            }
            __syncthreads();

            // ================= GEMM2 =================
            float4_ acc2[8][2];
            #pragma unroll
            for (int tt = 0; tt < 8; tt++) { acc2[tt][0] = fz; acc2[tt][1] = fz; }

            #pragma unroll
            for (int kc = 0; kc < 4; kc++) {
                int kb = (kc << 5) + (q << 3);
                short8 B00 = *(const short8*)(w2t + ((      colA) << 7) + kb);
                short8 B01 = *(const short8*)(w2t + ((128 + colA) << 7) + kb);
                short8 B10 = *(const short8*)(w2t + ((      colB) << 7) + kb);
                short8 B11 = *(const short8*)(w2t + ((128 + colB) << 7) + kb);
                #pragma unroll
                for (int tt = 0; tt < 8; tt++) {
                    short8 a = *(const short8*)(&hbuf[(tt << 4) + lr][kb]);
                    short8 Bx0 = ktile[tt] ? B01 : B00;
                    short8 Bx1 = ktile[tt] ? B11 : B10;
                    acc2[tt][0] = __builtin_amdgcn_mfma_f32_16x16x32_bf16(a, Bx0, acc2[tt][0], 0, 0, 0);
                    acc2[tt][1] = __builtin_amdgcn_mfma_f32_16x16x32_bf16(a, Bx1, acc2[tt][1], 0, 0, 0);
                }
            }
            // epilogue 2: bias + relu, pad-mask, edge reduction -> aggv
            float aggp[2][2] = {{0.f, 0.f}, {0.f, 0.f}};
            #pragma unroll
            for (int tt = 0; tt < 8; tt++) {
                int node = tt >> 2, r0 = q << 2;
                #pragma unroll
                for (int cw = 0; cw < 2; cw++) {
                    float bias = ktile[tt] ? (cw ? b2B1 : b2A1) : (cw ? b2B0 : b2A0);
                    float p = 0.f;
                    #pragma unroll
                    for (int i = 0; i < 4; i++) {
                        int jn = ((tt & 3) << 4) + r0 + i;
                        float mv = fmaxf(acc2[tt][cw][i] + bias, 0.f);
                        p += (jn < lim[tt]) ? mv : 0.f;
                    }
                    p += __shfl_down(p, 32);
                    p += __shfl_down(p, 16);
                    aggp[node][cw] += p;
                }
            }
            if (lane < 16) {
                #pragma unroll
                for (int node = 0; node < 2; node++)
                    #pragma unroll
                    for (int cw = 0; cw < 2; cw++)
                        aggv[node][((2 * w + cw) << 4) + lane] = aggp[node][cw];
            }
            __syncthreads();

            // ---- dy = tanh(agg/N @ W3 + b3); RK4 stage update (LDS state) ----
            if (tid < 128) {
                int node = tid >> 6, f = tid & 63;
                const float4_* av = (const float4_*)(&aggv[node][0]);
                float sacc = 0.f;
                #pragma unroll
                for (int c = 0; c < 16; c++) {
                    short8 wv = *(const short8*)(w3t + (f << 7) + (c << 3));
                    float4_ a0v = av[2 * c], a1v = av[2 * c + 1];
                    sacc += a0v[0] * bf2f((unsigned short)wv[0]);
                    sacc += a0v[1] * bf2f((unsigned short)wv[1]);
                    sacc += a0v[2] * bf2f((unsigned short)wv[2]);
                    sacc += a0v[3] * bf2f((unsigned short)wv[3]);
                    sacc += a1v[0] * bf2f((unsigned short)wv[4]);
                    sacc += a1v[1] * bf2f((unsigned short)wv[5]);
                    sacc += a1v[2] * bf2f((unsigned short)wv[6]);
                    sacc += a1v[3] * bf2f((unsigned short)wv[7]);
                }
                float xin = sacc * inv_n + b3v;
                float e  = __expf(2.0f * xin);
                float dy = 1.0f - 2.0f / (e + 1.0f);
                int bn = b * N_ + n0 + node;
                int sidx = vp * 128 + tid;
                float ybase = Ysh[sidx];
                float ysv;
                if (r == 0)      { Ash[sidx] = dy;          ysv = ybase + 0.5f * dt * dy; }
                else if (r == 1) { Ash[sidx] += 2.f * dy;   ysv = ybase + 0.5f * dt * dy; }
                else if (r == 2) { Ash[sidx] += 2.f * dy;   ysv = ybase + dt * dy; }
                else {
                    float yn = ybase + dt * (1.0f / 6.0f) * (Ash[sidx] + dy);
                    Ysh[sidx] = yn;
                    out[bn * (T_ * F_) + (t + 1) * F_ + f] = yn;
                    ysv = yn;
                }
                ybO[bn * F_ + f] = f2bf(ysv);
            }
            __syncthreads();   // protect hbuf/aggv/Ash reuse by next pair
        }

        // ---- per-batch barrier: makes ybO of all 4 peers visible ----
        __syncthreads();
        gen++;
        if (tid == 0) {
            __threadfence();   // drain/make visible this block's ybO stores
            __hip_atomic_fetch_add(cp, 1, __ATOMIC_RELEASE, __HIP_MEMORY_SCOPE_AGENT);
            while (__hip_atomic_load(cp, __ATOMIC_ACQUIRE, __HIP_MEMORY_SCOPE_AGENT) < 4 * gen)
                __builtin_amdgcn_s_sleep(2);
            __threadfence();   // acquire side
        }
        __syncthreads();
    }
}

// ---------------------------------------------------------------------------
extern "C" void kernel_launch(void* const* d_in, const int* in_sizes, int n_in,
                              void* d_out, int out_size, void* d_ws, size_t ws_size,
                              hipStream_t stream) {
    const float* fp    = (const float*)d_in[0];
    const float* ts    = (const float*)d_in[1];
    const int*   graph = (const int*)  d_in[2];
    const float* W1    = (const float*)d_in[3];
    const float* b1    = (const float*)d_in[4];
    const float* W2    = (const float*)d_in[5];
    const float* b2    = (const float*)d_in[6];
    const float* W3    = (const float*)d_in[7];
    const float* b3    = (const float*)d_in[8];
    float* out = (float*)d_out;

    char* ws = (char*)d_ws;
    size_t off = 0;
    auto alloc = [&](size_t bytes) {
        void* p = ws + off;
        off = (off + bytes + 255) & ~(size_t)255;
        return p;
    };
    unsigned short* ybG  = (unsigned short*)alloc(2 * B_ * N_ * F_ * 2);
    unsigned short* w1t  = (unsigned short*)alloc(32768 * 2);
    unsigned short* w2t  = (unsigned short*)alloc(32768 * 2);
    unsigned short* w3t  = (unsigned short*)alloc(8192 * 2);
    int*            slots = (int*)alloc(3200 * 64 * 4);
    int*            a0w   = (int*)alloc(3200 * 4);
    int*            cnt   = (int*)alloc(64 * 16 * 4);

    (void)hipMemsetAsync(cnt, 0, 64 * 16 * 4, stream);   // barrier counters = 0
    k_weights<<<256, 256, 0, stream>>>(W1, W2, w1t, w2t);
    k_w3<<<32, 256, 0, stream>>>(W3, w3t);
    k_sort<<<13, 256, 0, stream>>>(graph, slots, a0w);

    k_persist<<<256, 256, 0, stream>>>(fp, ts, slots, a0w, w1t, w2t, b1, b2,
                                       w3t, b3, ybG, out, cnt);
}